// Round 1
// baseline (1058.944 us; speedup 1.0000x reference)
//
#include <hip/hip_runtime.h>
#include <hip/hip_bf16.h>
#include <math.h>

// Problem constants (from reference)
#define S_   512
#define B_   32
#define D_   256
#define H_   8
#define DH_  32
#define E_   (H_*(5*DH_+2))   // 1296
#define SB_  (S_*B_)          // 16384
#define LN_EPSF 1e-5f

// ---------------- reductions ----------------
__device__ __forceinline__ float wave_sum64(float v){
  #pragma unroll
  for (int m = 32; m >= 1; m >>= 1) v += __shfl_xor(v, m, 64);
  return v;
}
__device__ __forceinline__ float gsum32(float v){
  #pragma unroll
  for (int m = 16; m >= 1; m >>= 1) v += __shfl_xor(v, m, 32);
  return v;
}
__device__ __forceinline__ float gmax32(float v){
  #pragma unroll
  for (int m = 16; m >= 1; m >>= 1) v = fmaxf(v, __shfl_xor(v, m, 32));
  return v;
}

// ---------------- LayerNorm: one block per (s,b) row ----------------
__global__ __launch_bounds__(256) void ln_kernel(const float* __restrict__ x,
                                                 const float* __restrict__ g,
                                                 const float* __restrict__ b,
                                                 float* __restrict__ o){
  __shared__ float sbuf[4];
  const int row = blockIdx.x, tid = threadIdx.x;
  const float v = x[(size_t)row*D_ + tid];
  float s = wave_sum64(v);
  if ((tid & 63) == 0) sbuf[tid >> 6] = s;
  __syncthreads();
  const float mu = (sbuf[0]+sbuf[1]+sbuf[2]+sbuf[3]) * (1.f/D_);
  __syncthreads();
  const float d = v - mu;
  float s2 = wave_sum64(d*d);
  if ((tid & 63) == 0) sbuf[tid >> 6] = s2;
  __syncthreads();
  const float var = (sbuf[0]+sbuf[1]+sbuf[2]+sbuf[3]) * (1.f/D_);
  const float rstd = rsqrtf(var + LN_EPSF);
  o[(size_t)row*D_ + tid] = d*rstd*g[tid] + b[tid];
}

// ---------------- GEMM (C[m][n] = sum_k A[m][k]*B[n][k] (+ X)) ----------------
// f32 vector-ALU, 128x128 tile, BK=16, 8x8 per thread, 256 threads.
template<bool ADD>
__global__ __launch_bounds__(256) void gemm_bt(const float* __restrict__ A,
                                               const float* __restrict__ Bm,
                                               const float* __restrict__ X,
                                               float* __restrict__ C,
                                               int M, int N, int K){
  const int BM=128, BN=128, BK=16;
  __shared__ float As[BK][BM+4];
  __shared__ float Bs[BK][BN+4];
  const int tid = threadIdx.x;
  const int m0 = blockIdx.y*BM, n0 = blockIdx.x*BN;
  const int tx = tid & 15, ty = tid >> 4;
  float acc[8][8];
  #pragma unroll
  for (int i=0;i<8;i++)
    #pragma unroll
    for (int j=0;j<8;j++) acc[i][j]=0.f;

  const int lrow = tid >> 2;         // 0..63
  const int lcol = (tid & 3) << 2;   // 0,4,8,12

  for (int k0=0;k0<K;k0+=BK){
    #pragma unroll
    for (int p=0;p<2;p++){
      const int row = lrow + p*64;
      const float4 va = *(const float4*)(A + (size_t)(m0+row)*K + k0 + lcol);
      As[lcol+0][row]=va.x; As[lcol+1][row]=va.y; As[lcol+2][row]=va.z; As[lcol+3][row]=va.w;
      const int nrow = n0 + row;
      float4 vb = make_float4(0.f,0.f,0.f,0.f);
      if (nrow < N) vb = *(const float4*)(Bm + (size_t)nrow*K + k0 + lcol);
      Bs[lcol+0][row]=vb.x; Bs[lcol+1][row]=vb.y; Bs[lcol+2][row]=vb.z; Bs[lcol+3][row]=vb.w;
    }
    __syncthreads();
    #pragma unroll
    for (int k=0;k<BK;k++){
      float a[8], bb[8];
      *(float4*)&a[0]  = *(const float4*)&As[k][ty*8];
      *(float4*)&a[4]  = *(const float4*)&As[k][ty*8+4];
      *(float4*)&bb[0] = *(const float4*)&Bs[k][tx*8];
      *(float4*)&bb[4] = *(const float4*)&Bs[k][tx*8+4];
      #pragma unroll
      for (int i=0;i<8;i++)
        #pragma unroll
        for (int j=0;j<8;j++) acc[i][j] = fmaf(a[i], bb[j], acc[i][j]);
    }
    __syncthreads();
  }
  #pragma unroll
  for (int i=0;i<8;i++){
    const size_t m = (size_t)(m0 + ty*8 + i);
    #pragma unroll
    for (int j=0;j<8;j+=4){
      const int n = n0 + tx*8 + j;
      if (n < N){   // N is a multiple of 4, n aligned to 4 -> float4 safe
        float4 r = make_float4(acc[i][j],acc[i][j+1],acc[i][j+2],acc[i][j+3]);
        if (ADD){
          const float4 xv = *(const float4*)(X + m*N + n);
          r.x+=xv.x; r.y+=xv.y; r.z+=xv.z; r.w+=xv.w;
        }
        *(float4*)(C + m*N + n) = r;
      }
    }
  }
}

// ---------------- activations, in-place on qkv [SB][H][162] ----------------
// per head chunk: q(0:32) k(32:64) v(64:96) rk(96:128) rv(128:160) beta(160) rbeta(161)
__global__ __launch_bounds__(256) void act_kernel(float* __restrict__ qkv){
  const int sb = blockIdx.x;
  const int head = threadIdx.x >> 5;   // 8 heads, 32 lanes each
  const int i = threadIdx.x & 31;
  float* base = qkv + (size_t)sb*E_ + head*(5*DH_+2);
  float qv  = base[i];
  float kv  = base[DH_ + i];
  float rkv = base[3*DH_ + i];
  qv = qv > 0.f ? qv + 1.f : __expf(qv);   // elu(x)+1
  kv = kv > 0.f ? kv + 1.f : __expf(kv);
  const float qs = gsum32(qv);
  const float ks = gsum32(kv);
  const float rm = gmax32(rkv);
  const float re = __expf(rkv - rm);
  const float rs = gsum32(re);
  base[i]         = qv / qs;
  base[DH_ + i]   = kv / ks;
  base[3*DH_ + i] = re / rs;
  if (i < 2){
    const float bv = base[5*DH_ + i];
    base[5*DH_ + i] = 1.f/(1.f + __expf(-bv));
  }
}

// ---------------- sequential scan: one wave per (b,h) pair ----------------
// lanes 0..31: row r of W (ff delta rule); lanes 32..63: row r of R (rec delta rule).
// Same code path on both halves (operand select only) -> no divergence in hot loop.
__global__ __launch_bounds__(64) void scan_kernel(const float* __restrict__ act,
                                                  float* __restrict__ hs){
  const int pair = blockIdx.x;        // b*H + h
  const int tid  = threadIdx.x;
  const int half = tid >> 5;          // 0: W, 1: R
  const int r    = tid & 31;

  float Mrow[DH_];
  #pragma unroll
  for (int i=0;i<DH_;i++) Mrow[i]=0.f;

  __shared__ float s_in[5*DH_+2];
  __shared__ float s_z[DH_];
  __shared__ float s_h[DH_];
  __shared__ float s_qr[DH_];

  if (tid < DH_) s_h[tid] = 0.f;
  __syncthreads();

  const float* p = act + (size_t)pair*(5*DH_+2);
  const size_t step_in = (size_t)B_*E_;
  float* hp = hs + (size_t)pair*DH_ + r;
  const size_t step_hs = (size_t)B_*H_*DH_;

  for (int s=0;s<S_;++s){
    // stage this step's 162 inputs
    #pragma unroll
    for (int j=tid; j<5*DH_+2; j+=64) s_in[j] = p[j];
    __syncthreads();

    // q_rec = softmax(h_prev) (both halves compute; upper half publishes)
    const float hv = s_h[r];
    const float mx = gmax32(hv);
    const float e  = __expf(hv - mx);
    const float es = gsum32(e);
    if (half) s_qr[r] = e / es;
    __syncthreads();

    const float* key = half ? (s_in + 3*DH_) : (s_in + DH_);   // rk : k
    const float  valr = half ? s_in[4*DH_ + r] : s_in[2*DH_ + r]; // rv[r] : v[r]
    const float* qry = half ? s_qr : s_in;                      // q_rec : q
    const float  bscal = s_in[5*DH_ + half];                    // rbeta : beta

    float kreg[DH_];
    #pragma unroll
    for (int c=0;c<DH_;c++) kreg[c] = key[c];

    // v_old = M[r,:] . key   (4-way split accumulators for ILP)
    float a0=0.f,a1=0.f,a2=0.f,a3=0.f;
    #pragma unroll
    for (int c=0;c<DH_;c+=4){
      a0 = fmaf(Mrow[c+0], kreg[c+0], a0);
      a1 = fmaf(Mrow[c+1], kreg[c+1], a1);
      a2 = fmaf(Mrow[c+2], kreg[c+2], a2);
      a3 = fmaf(Mrow[c+3], kreg[c+3], a3);
    }
    const float dot1 = (a0+a1)+(a2+a3);
    const float coef = bscal * (valr - dot1);

    // M[r,:] += coef*key ; out = M_new[r,:] . query
    float b0=0.f,b1=0.f,b2=0.f,b3=0.f;
    #pragma unroll
    for (int c=0;c<DH_;c+=4){
      Mrow[c+0] = fmaf(coef, kreg[c+0], Mrow[c+0]);
      Mrow[c+1] = fmaf(coef, kreg[c+1], Mrow[c+1]);
      Mrow[c+2] = fmaf(coef, kreg[c+2], Mrow[c+2]);
      Mrow[c+3] = fmaf(coef, kreg[c+3], Mrow[c+3]);
      b0 = fmaf(Mrow[c+0], qry[c+0], b0);
      b1 = fmaf(Mrow[c+1], qry[c+1], b1);
      b2 = fmaf(Mrow[c+2], qry[c+2], b2);
      b3 = fmaf(Mrow[c+3], qry[c+3], b3);
    }
    const float dot2 = (b0+b1)+(b2+b3);

    if (!half) s_z[r] = dot2;            // z_t
    __syncthreads();
    if (half){
      const float hval = s_z[r] + dot2;  // h_t = z_t + R@q_rec
      s_h[r] = hval;
      hp[(size_t)s*step_hs] = hval;
    }
    __syncthreads();
    p += step_in;
  }
}

// ---------------- launcher ----------------
extern "C" void kernel_launch(void* const* d_in, const int* in_sizes, int n_in,
                              void* d_out, int out_size, void* d_ws, size_t ws_size,
                              hipStream_t stream) {
  const float* x      = (const float*)d_in[0];
  const float* slow_W = (const float*)d_in[1];
  const float* out_W  = (const float*)d_in[2];
  const float* ln_g   = (const float*)d_in[3];
  const float* ln_b   = (const float*)d_in[4];
  float* out = (float*)d_out;

  // d_out doubles as the LN output buffer (consumed by GEMM1, then fully
  // overwritten by GEMM2's epilogue). Workspace: qkv (85MB) + hs (16.8MB).
  float* o   = out;
  float* qkv = (float*)d_ws;                 // [SB][E]
  float* hs  = qkv + (size_t)SB_*E_;         // [SB][D]

  ln_kernel<<<SB_, 256, 0, stream>>>(x, ln_g, ln_b, o);

  dim3 g1((E_ + 127)/128, SB_/128);          // (11, 128)
  gemm_bt<false><<<g1, 256, 0, stream>>>(o, slow_W, nullptr, qkv, SB_, E_, D_);

  act_kernel<<<SB_, 256, 0, stream>>>(qkv);

  scan_kernel<<<B_*H_, 64, 0, stream>>>(qkv, hs);

  dim3 g2(D_/128, SB_/128);                  // (2, 128)
  gemm_bt<true><<<g2, 256, 0, stream>>>(hs, out_W, x, out, SB_, D_, D_);
}

// Round 2
// 622.553 us; speedup vs baseline: 1.7010x; 1.7010x over previous
//
#include <hip/hip_runtime.h>
#include <hip/hip_bf16.h>
#include <math.h>

// Problem constants (from reference)
#define S_   512
#define B_   32
#define D_   256
#define H_   8
#define DH_  32
#define E_   (H_*(5*DH_+2))   // 1296
#define SB_  (S_*B_)          // 16384
#define LN_EPSF 1e-5f
#define PF_  4                // scan prefetch distance (steps)

// ---------------- reductions ----------------
__device__ __forceinline__ float wave_sum64(float v){
  #pragma unroll
  for (int m = 32; m >= 1; m >>= 1) v += __shfl_xor(v, m, 64);
  return v;
}
__device__ __forceinline__ float gsum32(float v){
  #pragma unroll
  for (int m = 16; m >= 1; m >>= 1) v += __shfl_xor(v, m, 32);
  return v;
}
__device__ __forceinline__ float gmax32(float v){
  #pragma unroll
  for (int m = 16; m >= 1; m >>= 1) v = fmaxf(v, __shfl_xor(v, m, 32));
  return v;
}

// ---------------- LayerNorm: one block per (s,b) row ----------------
__global__ __launch_bounds__(256) void ln_kernel(const float* __restrict__ x,
                                                 const float* __restrict__ g,
                                                 const float* __restrict__ b,
                                                 float* __restrict__ o){
  __shared__ float sbuf[4];
  const int row = blockIdx.x, tid = threadIdx.x;
  const float v = x[(size_t)row*D_ + tid];
  float s = wave_sum64(v);
  if ((tid & 63) == 0) sbuf[tid >> 6] = s;
  __syncthreads();
  const float mu = (sbuf[0]+sbuf[1]+sbuf[2]+sbuf[3]) * (1.f/D_);
  __syncthreads();
  const float d = v - mu;
  float s2 = wave_sum64(d*d);
  if ((tid & 63) == 0) sbuf[tid >> 6] = s2;
  __syncthreads();
  const float var = (sbuf[0]+sbuf[1]+sbuf[2]+sbuf[3]) * (1.f/D_);
  const float rstd = rsqrtf(var + LN_EPSF);
  o[(size_t)row*D_ + tid] = d*rstd*g[tid] + b[tid];
}

// ---------------- GEMM (C[m][n] = sum_k A[m][k]*B[n][k] (+ X)) ----------------
// f32 vector-ALU, 128x128 tile, BK=16, 8x8 per thread, 256 threads.
template<bool ADD>
__global__ __launch_bounds__(256) void gemm_bt(const float* __restrict__ A,
                                               const float* __restrict__ Bm,
                                               const float* __restrict__ X,
                                               float* __restrict__ C,
                                               int M, int N, int K){
  const int BM=128, BN=128, BK=16;
  __shared__ float As[BK][BM+4];
  __shared__ float Bs[BK][BN+4];
  const int tid = threadIdx.x;
  const int m0 = blockIdx.y*BM, n0 = blockIdx.x*BN;
  const int tx = tid & 15, ty = tid >> 4;
  float acc[8][8];
  #pragma unroll
  for (int i=0;i<8;i++)
    #pragma unroll
    for (int j=0;j<8;j++) acc[i][j]=0.f;

  const int lrow = tid >> 2;         // 0..63
  const int lcol = (tid & 3) << 2;   // 0,4,8,12

  for (int k0=0;k0<K;k0+=BK){
    #pragma unroll
    for (int p=0;p<2;p++){
      const int row = lrow + p*64;
      const float4 va = *(const float4*)(A + (size_t)(m0+row)*K + k0 + lcol);
      As[lcol+0][row]=va.x; As[lcol+1][row]=va.y; As[lcol+2][row]=va.z; As[lcol+3][row]=va.w;
      const int nrow = n0 + row;
      float4 vb = make_float4(0.f,0.f,0.f,0.f);
      if (nrow < N) vb = *(const float4*)(Bm + (size_t)nrow*K + k0 + lcol);
      Bs[lcol+0][row]=vb.x; Bs[lcol+1][row]=vb.y; Bs[lcol+2][row]=vb.z; Bs[lcol+3][row]=vb.w;
    }
    __syncthreads();
    #pragma unroll
    for (int k=0;k<BK;k++){
      float a[8], bb[8];
      *(float4*)&a[0]  = *(const float4*)&As[k][ty*8];
      *(float4*)&a[4]  = *(const float4*)&As[k][ty*8+4];
      *(float4*)&bb[0] = *(const float4*)&Bs[k][tx*8];
      *(float4*)&bb[4] = *(const float4*)&Bs[k][tx*8+4];
      #pragma unroll
      for (int i=0;i<8;i++)
        #pragma unroll
        for (int j=0;j<8;j++) acc[i][j] = fmaf(a[i], bb[j], acc[i][j]);
    }
    __syncthreads();
  }
  #pragma unroll
  for (int i=0;i<8;i++){
    const size_t m = (size_t)(m0 + ty*8 + i);
    #pragma unroll
    for (int j=0;j<8;j+=4){
      const int n = n0 + tx*8 + j;
      if (n < N){   // N is a multiple of 4, n aligned to 4 -> float4 safe
        float4 r = make_float4(acc[i][j],acc[i][j+1],acc[i][j+2],acc[i][j+3]);
        if (ADD){
          const float4 xv = *(const float4*)(X + m*N + n);
          r.x+=xv.x; r.y+=xv.y; r.z+=xv.z; r.w+=xv.w;
        }
        *(float4*)(C + m*N + n) = r;
      }
    }
  }
}

// ---------------- activations, in-place on qkv [SB][H][162] ----------------
// per head chunk: q(0:32) k(32:64) v(64:96) rk(96:128) rv(128:160) beta(160) rbeta(161)
__global__ __launch_bounds__(256) void act_kernel(float* __restrict__ qkv){
  const int sb = blockIdx.x;
  const int head = threadIdx.x >> 5;   // 8 heads, 32 lanes each
  const int i = threadIdx.x & 31;
  float* base = qkv + (size_t)sb*E_ + head*(5*DH_+2);
  float qv  = base[i];
  float kv  = base[DH_ + i];
  float rkv = base[3*DH_ + i];
  qv = qv > 0.f ? qv + 1.f : __expf(qv);   // elu(x)+1
  kv = kv > 0.f ? kv + 1.f : __expf(kv);
  const float qs = gsum32(qv);
  const float ks = gsum32(kv);
  const float rm = gmax32(rkv);
  const float re = __expf(rkv - rm);
  const float rs = gsum32(re);
  base[i]         = qv / qs;
  base[DH_ + i]   = kv / ks;
  base[3*DH_ + i] = re / rs;
  if (i < 2){
    const float bv = base[5*DH_ + i];
    base[5*DH_ + i] = 1.f/(1.f + __expf(-bv));
  }
}

// ---------------- sequential scan: one wave per (b,h) pair ----------------
// Latency-optimized: chain count is fixed at B*H=256 (= 1 wave/CU), so wall
// time = 512 * per-step critical path. Design:
//  - lanes 0..31 run the W (ff) chain, lanes 32..63 the R (rec) chain, in
//    lockstep (operand select only, no divergence in the hot loop)
//  - per-lane register prefetch of the step inputs, distance PF_=4 -> global
//    (L3) latency off the critical path
//  - single wave per block: NO __syncthreads; LDS only as a 32-lane broadcast
//    medium (lane writes 1 value, all lanes read back via same-address
//    float4 broadcasts = conflict-free ds_read_b128; waitcnt-ordered)
//  - softmax(h) folded as (sum_c R[r][c]*e_c) * (1/S): the 5-shuffle S-reduce
//    runs in parallel with the R.e dot; no max-subtraction (h is delta-rule
//    bounded, far from exp overflow; softmax is shift-invariant)
__global__ __launch_bounds__(64) void scan_kernel(const float* __restrict__ act,
                                                  float* __restrict__ hs){
  const int pair = blockIdx.x;        // b*H + h
  const int tid  = threadIdx.x;
  const int half = tid >> 5;          // 0: W chain, 1: R chain
  const int r    = tid & 31;

  __shared__ __align__(16) float s_key[2][DH_];
  __shared__ __align__(16) float s_qry[2][DH_];

  float Mrow[DH_];
  #pragma unroll
  for (int i=0;i<DH_;i++) Mrow[i]=0.f;
  float hreg = 0.f;                   // h state (valid in half1; 0 in half0)

  const float* base = act + (size_t)pair*(5*DH_+2);
  const size_t step_in = (size_t)B_*E_;
  const int okey = (half ? 3*DH_ : DH_)   + r;   // rk : k
  const int oval = (half ? 4*DH_ : 2*DH_) + r;   // rv : v
  const int oqry = r;                            // q (half0 only; half1 ignores)
  const int obet = 5*DH_ + half;                 // beta : rbeta

  // prefetch buffers, fully unrolled indexing (never runtime-indexed)
  float fk[PF_], fv[PF_], fq[PF_], fb[PF_];
  #pragma unroll
  for (int u=0;u<PF_;u++){
    const float* pp = base + (size_t)u*step_in;
    fk[u]=pp[okey]; fv[u]=pp[oval]; fq[u]=pp[oqry]; fb[u]=pp[obet];
  }

  float* hp = hs + (size_t)pair*DH_ + r;
  const size_t step_hs = (size_t)B_*H_*DH_;

  for (int sc=0; sc<S_; sc+=PF_){
    #pragma unroll
    for (int u=0; u<PF_; ++u){
      const int s = sc + u;
      const float keyv=fk[u], valv=fv[u], qv=fq[u], bscal=fb[u];
      if (s + PF_ < S_){                     // uniform branch
        const float* pp = base + (size_t)(s+PF_)*step_in;
        fk[u]=pp[okey]; fv[u]=pp[oval]; fq[u]=pp[oqry]; fb[u]=pp[obet];
      }

      // half1: e = exp(h_prev); half0: exp(0)=1, harmless
      const float e = __expf(hreg);
      s_key[half][r] = keyv;
      s_qry[half][r] = half ? e : qv;

      // S = sum(e) over the 32 R-lanes; runs in parallel with the dots below
      float Ssum = e;
      #pragma unroll
      for (int m=16;m>=1;m>>=1) Ssum += __shfl_xor(Ssum, m, 32);
      const float rcpS = 1.f / Ssum;

      // broadcast-read this half's key vector (same-address -> no conflicts)
      float kk[DH_];
      #pragma unroll
      for (int c4=0;c4<DH_/4;c4++)
        *(float4*)&kk[c4*4] = *(const float4*)&s_key[half][c4*4];

      // v_old[r] = M[r,:] . key
      float a0=0.f,a1=0.f,a2=0.f,a3=0.f;
      #pragma unroll
      for (int c=0;c<DH_;c+=4){
        a0=fmaf(Mrow[c+0],kk[c+0],a0); a1=fmaf(Mrow[c+1],kk[c+1],a1);
        a2=fmaf(Mrow[c+2],kk[c+2],a2); a3=fmaf(Mrow[c+3],kk[c+3],a3);
      }
      const float coef = bscal*(valv-((a0+a1)+(a2+a3)));

      // M[r,:] += coef*key ; dot2[r] = M_new[r,:] . qry   (qry: q | e)
      float b0=0.f,b1=0.f,b2=0.f,b3=0.f;
      #pragma unroll
      for (int c4=0;c4<DH_/4;c4++){
        const float4 qc = *(const float4*)&s_qry[half][c4*4];
        const int c=c4*4;
        Mrow[c+0]=fmaf(coef,kk[c+0],Mrow[c+0]); b0=fmaf(Mrow[c+0],qc.x,b0);
        Mrow[c+1]=fmaf(coef,kk[c+1],Mrow[c+1]); b1=fmaf(Mrow[c+1],qc.y,b1);
        Mrow[c+2]=fmaf(coef,kk[c+2],Mrow[c+2]); b2=fmaf(Mrow[c+2],qc.z,b2);
        Mrow[c+3]=fmaf(coef,kk[c+3],Mrow[c+3]); b3=fmaf(Mrow[c+3],qc.w,b3);
      }
      const float dot2 = (b0+b1)+(b2+b3);

      // z (half0's dot2) to everyone; half1 forms h = z + (R.e)/S
      const float zval = __shfl(dot2, r, 64);
      if (half){
        const float hnew = zval + dot2*rcpS;
        hreg = hnew;
        hp[(size_t)s*step_hs] = hnew;      // 128B contiguous per half-wave
      }
    }
  }
}

// ---------------- launcher ----------------
extern "C" void kernel_launch(void* const* d_in, const int* in_sizes, int n_in,
                              void* d_out, int out_size, void* d_ws, size_t ws_size,
                              hipStream_t stream) {
  const float* x      = (const float*)d_in[0];
  const float* slow_W = (const float*)d_in[1];
  const float* out_W  = (const float*)d_in[2];
  const float* ln_g   = (const float*)d_in[3];
  const float* ln_b   = (const float*)d_in[4];
  float* out = (float*)d_out;

  // d_out doubles as the LN output buffer (consumed by GEMM1, then fully
  // overwritten by GEMM2's epilogue). Workspace: qkv (85MB) + hs (16.8MB).
  float* o   = out;
  float* qkv = (float*)d_ws;                 // [SB][E]
  float* hs  = qkv + (size_t)SB_*E_;         // [SB][D]

  ln_kernel<<<SB_, 256, 0, stream>>>(x, ln_g, ln_b, o);

  dim3 g1((E_ + 127)/128, SB_/128);          // (11, 128)
  gemm_bt<false><<<g1, 256, 0, stream>>>(o, slow_W, nullptr, qkv, SB_, E_, D_);

  act_kernel<<<SB_, 256, 0, stream>>>(qkv);

  scan_kernel<<<B_*H_, 64, 0, stream>>>(qkv, hs);

  dim3 g2(D_/128, SB_/128);                  // (2, 128)
  gemm_bt<true><<<g2, 256, 0, stream>>>(hs, out_W, x, out, SB_, D_, D_);
}